// Round 13
// baseline (144.365 us; speedup 1.0000x reference)
//
#include <hip/hip_runtime.h>

// SlotElmanCell: T=1024, Bb=2, D=1024, S=64
//   decay = sigmoid(decay_logits)            [D,S]
//   h[t+1] = decay*h[t] + B*x[t]             [Bb,D,S]
//   out[t] = (h[t+1] . C) * silu(z[t])       [Bb,D]
// Outputs (concat flat): out [T,Bb,D] then h [T+1,Bb,D,S]  (f32)
//
// R13 = R12 with the out-reduction moved OUT of the serial step loop into
// the flush phase. Step loop is now 4 instrs (readlane, mul, fmaf,
// ds_write). Flush wave re-reads the staged tile (needed for the h store
// anyway) and computes the 16 dots via 4-FMA local dot + 4-stage row_shr
// DPP reduce; z read row-wise at flush (once, same bytes); out nt-stored
// from the 4 result lanes. Per-CU compute-issue ~57us -> ~25us, under the
// ~82us store floor.

#define T_    1024
#define BB_   2
#define D_    1024
#define S_    64
#define SEG_  64              // steps per segment
#define NSEG_ (T_ / SEG_)     // 16
#define NCH_  (BB_ * D_)      // 2048 chains
#define STRD_ (BB_ * D_)      // x/z stride between timesteps
#define CHB_  16              // chains per pass2 block
#define FG_   16              // steps per flush group
#define WS_NEED_ ((size_t)NCH_ * NSEG_ * S_ * 4)   // 8 MB

typedef float f32x4 __attribute__((ext_vector_type(4)));

// Barrier that does NOT drain vmcnt (LDS ordering only).
#define LDS_BARRIER() asm volatile("s_waitcnt lgkmcnt(0)\n\ts_barrier" ::: "memory")

// x + dpp_shifted(x); bound_ctrl=1 -> out-of-range sources read 0.
#define DPP_ADD(x, ctrl, rm) \
  ((x) + __int_as_float(__builtin_amdgcn_update_dpp( \
        0, __float_as_int(x), (ctrl), (rm), 0xf, true)))

__device__ __forceinline__ float readlane_f(float v, int lane) {
    return __int_as_float(__builtin_amdgcn_readlane(__float_as_int(v), lane));
}

__device__ __forceinline__ float sigmoidf_(float v) {
    return 1.0f / (1.0f + __expf(-v));
}

__device__ __forceinline__ void nt_store4(float* p, f32x4 v) {
    __builtin_nontemporal_store(v, (f32x4*)p);
}
__device__ __forceinline__ void nt_store1(float* p, float v) {
    __builtin_nontemporal_store(v, p);
}

// ---------------- Pass 1: per-segment local scans (zero init) -------------
__global__ __launch_bounds__(256, 8) void slot_elman_pass1(
    const float* __restrict__ x, const float* __restrict__ dl,
    const float* __restrict__ Bm, float* __restrict__ ws)
{
    const int wave = blockIdx.x * (blockDim.x >> 6) + (threadIdx.x >> 6);
    const int lane = threadIdx.x & 63;
    const int bd   = wave & (NCH_ - 1);     // chain
    const int seg  = wave >> 11;            // segment
    const int d    = bd & (D_ - 1);
    const int ds   = d * S_ + lane;

    const float decay = sigmoidf_(dl[ds]);
    const float Bv    = Bm[ds];

    const float xg = x[(size_t)(seg * SEG_ + lane) * STRD_ + bd];

    float hl = 0.0f;
    #pragma unroll
    for (int i = 0; i < SEG_; ++i)
        hl = fmaf(decay, hl, Bv * readlane_f(xg, i));

    ws[(size_t)(bd * NSEG_ + seg) * S_ + lane] = hl;   // regular store (re-read)
}

// ---------------- Pass 2: fold start state, scan, staged writes -----------
__global__ __launch_bounds__(1024, 8) void slot_elman_pass2(
    const float* __restrict__ x, const float* __restrict__ z,
    const float* __restrict__ h0, const float* __restrict__ dl,
    const float* __restrict__ Bm, const float* __restrict__ C,
    const float* __restrict__ ws,
    float* __restrict__ out, float* __restrict__ h)
{
    __shared__ float stage[FG_ * CHB_ * S_];   // 64 KB

    // Seg-major ordering (R7, confirmed): resident window = few segments
    // with all 128 chain-groups -> contiguous 512KB t-slice sweeps.
    const int bid = blockIdx.x;
    const int seg = bid >> 7;                       // 0..15
    const int g   = bid & 127;                      // chain group

    const int w    = threadIdx.x >> 6;              // wave 0..15
    const int lane = threadIdx.x & 63;              // slot s
    const int bd   = g * CHB_ + w;
    const int d    = bd & (D_ - 1);
    const int ds   = d * S_ + lane;

    const float decay = sigmoidf_(dl[ds]);
    const float Bv    = Bm[ds];

    // C fragment for the flush-phase dot: lane covers slots 4*(lane&15)..+3
    const f32x4 cv = *(const f32x4*)&C[4 * (lane & 15)];

    // decay^64 by repeated squaring
    float dk = decay * decay;
    dk = dk * dk; dk = dk * dk; dk = dk * dk; dk = dk * dk;
    const float d64 = dk * dk;

    // Segment start state: h0 folded with previous segments' local sums.
    float hv = h0[(size_t)bd * S_ + lane];
    if (seg == 0)
        nt_store1(&h[(size_t)bd * S_ + lane], hv);  // h[0] slice

    const float* wp = ws + (size_t)bd * NSEG_ * S_ + lane;
    #pragma unroll
    for (int j = 0; j < NSEG_ - 1; ++j) {
        const float lj = wp[(size_t)j * S_];
        const float wgt = (j < seg) ? d64 : 1.0f;
        const float add = (j < seg) ? lj  : 0.0f;
        hv = fmaf(wgt, hv, add);
    }

    // x gather: lane l covers t = seg*64 + l
    const float xgA = x[(size_t)(seg * SEG_ + lane) * STRD_ + bd];

    for (int f = 0; f < SEG_ / FG_; ++f) {          // 4 groups of 16 steps
        #pragma unroll
        for (int li = 0; li < FG_; ++li) {
            const int i = f * FG_ + li;             // segment-local step
            const float xs = readlane_f(xgA, i);    // broadcast x[t]
            hv = fmaf(decay, hv, Bv * xs);          // recurrence
            stage[(li * CHB_ + w) * S_ + lane] = hv; // stage h row
        }

        LDS_BARRIER();   // stage writes visible; global stores NOT drained

        // Flush + out: wave w owns t-slice li=w (t = seg*64 + f*16 + w).
        // h: ONE contiguous 4KB chunk (nt). out: 16 dots computed from the
        // same register data via 4-FMA local dot + row_shr DPP reduce.
        {
            const int t  = seg * SEG_ + f * FG_ + w;   // out index
            const float* src = &stage[w * CHB_ * S_];
            float* dst = &h[((size_t)(t + 1) * NCH_ + (size_t)g * CHB_) * S_];
            const int o = lane * 4;                 // 64 lanes x 4 floats

            #pragma unroll
            for (int b = 0; b < 4; ++b) {
                const f32x4 v = *(const f32x4*)(src + o + b * 256);
                nt_store4(dst + o + b * 256, v);

                // local dot with C fragment
                float pd = v.x * cv.x;
                pd = fmaf(v.y, cv.y, pd);
                pd = fmaf(v.z, cv.z, pd);
                pd = fmaf(v.w, cv.w, pd);
                // 16-lane row reduce -> lane 15 of each row
                pd = DPP_ADD(pd, 0x111, 0xf);  // row_shr:1
                pd = DPP_ADD(pd, 0x112, 0xf);  // row_shr:2
                pd = DPP_ADD(pd, 0x114, 0xf);  // row_shr:4
                pd = DPP_ADD(pd, 0x118, 0xf);  // row_shr:8

                if ((lane & 15) == 15) {
                    const int chain = b * 4 + (lane >> 4);
                    const size_t oi = (size_t)t * STRD_ + (size_t)g * CHB_ + chain;
                    const float zv = z[oi];
                    nt_store1(&out[oi], pd * (zv * sigmoidf_(zv)));
                }
            }
        }

        LDS_BARRIER();   // stage reads done; safe to overwrite next group
    }
}

// ---------------- Fallback (R4 single kernel) if ws too small -------------
__global__ __launch_bounds__(256, 2) void slot_elman_fallback(
    const float* __restrict__ x, const float* __restrict__ z,
    const float* __restrict__ h0, const float* __restrict__ dl,
    const float* __restrict__ Bm, const float* __restrict__ C,
    float* __restrict__ out, float* __restrict__ h)
{
    const int nb  = gridDim.x;
    const int cpx = nb >> 3;
    const int bid = blockIdx.x;
    const int swz = (bid & 7) * cpx + (bid >> 3);

    const int wave = swz * (blockDim.x >> 6) + (threadIdx.x >> 6);
    const int lane = threadIdx.x & 63;
    const int bd = wave & (NCH_ - 1);
    const int d  = bd & (D_ - 1);
    const int ds = d * S_ + lane;

    const float decay = sigmoidf_(dl[ds]);
    const float Bv    = Bm[ds];
    const float Cv    = C[lane];

    float hv = h0[(size_t)bd * S_ + lane];
    h[(size_t)bd * S_ + lane] = hv;

    const float* xg_p = x + (size_t)lane * STRD_ + bd;
    const float* zg_p = z + (size_t)lane * STRD_ + bd;
    float*       hp = h + (size_t)(NCH_ * S_) + (size_t)bd * S_ + lane;
    float*       op = out + (size_t)lane * STRD_ + bd;

    float xgA = xg_p[0];
    float zgA = zg_p[0];

    for (int blk = 0; blk < NSEG_; ++blk) {
        const int tb = blk * SEG_;
        const int tbn = (blk + 1 < NSEG_) ? (tb + SEG_) : tb;
        const float xgB = xg_p[(size_t)tbn * STRD_];
        const float zgB = zg_p[(size_t)tbn * STRD_];

        const float sgv = zgA * sigmoidf_(zgA);
        float outacc = 0.0f;

        #pragma unroll 8
        for (int i = 0; i < SEG_; ++i) {
            const float xs = readlane_f(xgA, i);
            hv = fmaf(decay, hv, Bv * xs);
            hp[(size_t)(tb + i) * (NCH_ * S_)] = hv;

            float p = hv * Cv;
            p = DPP_ADD(p, 0x111, 0xf);
            p = DPP_ADD(p, 0x112, 0xf);
            p = DPP_ADD(p, 0x114, 0xf);
            p = DPP_ADD(p, 0x118, 0xf);
            p = DPP_ADD(p, 0x142, 0xa);
            p = DPP_ADD(p, 0x143, 0xc);

            const float ov = p * readlane_f(sgv, i);
            const float bc = readlane_f(ov, 63);
            outacc = (lane == i) ? bc : outacc;
        }
        op[(size_t)tb * STRD_] = outacc;
        xgA = xgB; zgA = zgB;
    }
}

extern "C" void kernel_launch(void* const* d_in, const int* in_sizes, int n_in,
                              void* d_out, int out_size, void* d_ws, size_t ws_size,
                              hipStream_t stream) {
    const float* x  = (const float*)d_in[0];   // [T,Bb,D]
    const float* z  = (const float*)d_in[1];   // [T,Bb,D]
    const float* h0 = (const float*)d_in[2];   // [Bb,D,S]
    const float* dl = (const float*)d_in[3];   // [D,S]
    const float* Bm = (const float*)d_in[4];   // [D,S]
    const float* C  = (const float*)d_in[5];   // [S]

    float* out = (float*)d_out;                            // [T,Bb,D]
    float* h   = (float*)d_out + (size_t)T_ * BB_ * D_;    // [T+1,Bb,D,S]

    if (ws_size >= WS_NEED_) {
        float* ws = (float*)d_ws;
        const int waves1 = NCH_ * NSEG_;          // 32768
        const int grid1  = waves1 * 64 / 256;     // 8192
        hipLaunchKernelGGL(slot_elman_pass1, dim3(grid1), dim3(256), 0, stream,
                           x, dl, Bm, ws);
        const int grid2  = (NCH_ / CHB_) * NSEG_; // 128 * 16 = 2048
        hipLaunchKernelGGL(slot_elman_pass2, dim3(grid2), dim3(1024), 0, stream,
                           x, z, h0, dl, Bm, C, ws, out, h);
    } else {
        const int waves = NCH_;                   // 2048
        const int grid  = waves * 64 / 256;       // 512
        hipLaunchKernelGGL(slot_elman_fallback, dim3(grid), dim3(256), 0, stream,
                           x, z, h0, dl, Bm, C, out, h);
    }
}

// Round 14
// 140.231 us; speedup vs baseline: 1.0295x; 1.0295x over previous
//
#include <hip/hip_runtime.h>

// SlotElmanCell: T=1024, Bb=2, D=1024, S=64
//   decay = sigmoid(decay_logits)            [D,S]
//   h[t+1] = decay*h[t] + B*x[t]             [Bb,D,S]
//   out[t] = (h[t+1] . C) * silu(z[t])       [Bb,D]
// Outputs (concat flat): out [T,Bb,D] then h [T+1,Bb,D,S]  (f32)
//
// R14 = R13's flush-phase out-reduction, but with silu(z) staged in LDS
// from the up-front per-wave z gather (latency hidden under the ws fold),
// instead of R13's 16 exposed scalar z loads per wave in the flush path
// (the cause of the 114->144 regression).
//  - step loop: readlane + mul + fmaf + ds_write (4 instrs)
//  - flush: h tile ds_read (needed for store anyway) -> nt_store 4KB chunk
//    + 4-FMA local dot + 4-stage row_shr DPP + LDS silu read -> nt out store

#define T_    1024
#define BB_   2
#define D_    1024
#define S_    64
#define SEG_  64              // steps per segment
#define NSEG_ (T_ / SEG_)     // 16
#define NCH_  (BB_ * D_)      // 2048 chains
#define STRD_ (BB_ * D_)      // x/z stride between timesteps
#define CHB_  16              // chains per pass2 block
#define FG_   16              // steps per flush group
#define WS_NEED_ ((size_t)NCH_ * NSEG_ * S_ * 4)   // 8 MB

typedef float f32x4 __attribute__((ext_vector_type(4)));

// Barrier that does NOT drain vmcnt (LDS ordering only).
#define LDS_BARRIER() asm volatile("s_waitcnt lgkmcnt(0)\n\ts_barrier" ::: "memory")

// x + dpp_shifted(x); bound_ctrl=1 -> out-of-range sources read 0.
#define DPP_ADD(x, ctrl, rm) \
  ((x) + __int_as_float(__builtin_amdgcn_update_dpp( \
        0, __float_as_int(x), (ctrl), (rm), 0xf, true)))

__device__ __forceinline__ float readlane_f(float v, int lane) {
    return __int_as_float(__builtin_amdgcn_readlane(__float_as_int(v), lane));
}

__device__ __forceinline__ float sigmoidf_(float v) {
    return 1.0f / (1.0f + __expf(-v));
}

__device__ __forceinline__ void nt_store4(float* p, f32x4 v) {
    __builtin_nontemporal_store(v, (f32x4*)p);
}
__device__ __forceinline__ void nt_store1(float* p, float v) {
    __builtin_nontemporal_store(v, p);
}

// ---------------- Pass 1: per-segment local scans (zero init) -------------
__global__ __launch_bounds__(256, 8) void slot_elman_pass1(
    const float* __restrict__ x, const float* __restrict__ dl,
    const float* __restrict__ Bm, float* __restrict__ ws)
{
    const int wave = blockIdx.x * (blockDim.x >> 6) + (threadIdx.x >> 6);
    const int lane = threadIdx.x & 63;
    const int bd   = wave & (NCH_ - 1);     // chain
    const int seg  = wave >> 11;            // segment
    const int d    = bd & (D_ - 1);
    const int ds   = d * S_ + lane;

    const float decay = sigmoidf_(dl[ds]);
    const float Bv    = Bm[ds];

    const float xg = x[(size_t)(seg * SEG_ + lane) * STRD_ + bd];

    float hl = 0.0f;
    #pragma unroll
    for (int i = 0; i < SEG_; ++i)
        hl = fmaf(decay, hl, Bv * readlane_f(xg, i));

    ws[(size_t)(bd * NSEG_ + seg) * S_ + lane] = hl;   // regular store (re-read)
}

// ---------------- Pass 2: fold start state, scan, staged writes -----------
__global__ __launch_bounds__(1024, 8) void slot_elman_pass2(
    const float* __restrict__ x, const float* __restrict__ z,
    const float* __restrict__ h0, const float* __restrict__ dl,
    const float* __restrict__ Bm, const float* __restrict__ C,
    const float* __restrict__ ws,
    float* __restrict__ out, float* __restrict__ h)
{
    __shared__ float stage[FG_ * CHB_ * S_];   // 64 KB
    __shared__ float sz[CHB_ * 65];            // silu(z): [chain][t], pad 65

    // Seg-major ordering (R7, confirmed): resident window = few segments
    // with all 128 chain-groups -> contiguous 512KB t-slice sweeps.
    const int bid = blockIdx.x;
    const int seg = bid >> 7;                       // 0..15
    const int g   = bid & 127;                      // chain group

    const int w    = threadIdx.x >> 6;              // wave 0..15
    const int lane = threadIdx.x & 63;              // slot s
    const int bd   = g * CHB_ + w;
    const int d    = bd & (D_ - 1);
    const int ds   = d * S_ + lane;

    const float decay = sigmoidf_(dl[ds]);
    const float Bv    = Bm[ds];

    // C fragment for the flush-phase dot: lane covers slots 4*(lane&15)..+3
    const f32x4 cv = *(const f32x4*)&C[4 * (lane & 15)];

    // decay^64 by repeated squaring
    float dk = decay * decay;
    dk = dk * dk; dk = dk * dk; dk = dk * dk; dk = dk * dk;
    const float d64 = dk * dk;

    // Gathers (issued up-front; latency hides under the ws fold below):
    // lane l covers t = seg*64 + l for this wave's chain bd.
    const float xgA = x[(size_t)(seg * SEG_ + lane) * STRD_ + bd];
    const float zgA = z[(size_t)(seg * SEG_ + lane) * STRD_ + bd];

    // Segment start state: h0 folded with previous segments' local sums.
    float hv = h0[(size_t)bd * S_ + lane];
    if (seg == 0)
        nt_store1(&h[(size_t)bd * S_ + lane], hv);  // h[0] slice

    const float* wp = ws + (size_t)bd * NSEG_ * S_ + lane;
    #pragma unroll
    for (int j = 0; j < NSEG_ - 1; ++j) {
        const float lj = wp[(size_t)j * S_];
        const float wgt = (j < seg) ? d64 : 1.0f;
        const float add = (j < seg) ? lj  : 0.0f;
        hv = fmaf(wgt, hv, add);
    }

    // silu(z) for this chain, all 64 t (lane = t) -> LDS table [chain][t]
    sz[w * 65 + lane] = zgA * sigmoidf_(zgA);

    for (int f = 0; f < SEG_ / FG_; ++f) {          // 4 groups of 16 steps
        #pragma unroll
        for (int li = 0; li < FG_; ++li) {
            const int i = f * FG_ + li;             // segment-local step
            const float xs = readlane_f(xgA, i);    // broadcast x[t]
            hv = fmaf(decay, hv, Bv * xs);          // recurrence
            stage[(li * CHB_ + w) * S_ + lane] = hv; // stage h row
        }

        LDS_BARRIER();   // stage (+sz on f=0) visible; stores NOT drained

        // Flush + out: wave w owns t-slice li=w (t = seg*64 + f*16 + w).
        {
            const int t  = seg * SEG_ + f * FG_ + w;   // out index
            const int tl = f * FG_ + w;                // t within segment
            const float* src = &stage[w * CHB_ * S_];
            float* dst = &h[((size_t)(t + 1) * NCH_ + (size_t)g * CHB_) * S_];
            const int o = lane * 4;                 // 64 lanes x 4 floats

            #pragma unroll
            for (int b = 0; b < 4; ++b) {
                const f32x4 v = *(const f32x4*)(src + o + b * 256);
                nt_store4(dst + o + b * 256, v);

                // local dot with C fragment
                float pd = v.x * cv.x;
                pd = fmaf(v.y, cv.y, pd);
                pd = fmaf(v.z, cv.z, pd);
                pd = fmaf(v.w, cv.w, pd);
                // 16-lane row reduce -> lane 15 of each row
                pd = DPP_ADD(pd, 0x111, 0xf);  // row_shr:1
                pd = DPP_ADD(pd, 0x112, 0xf);  // row_shr:2
                pd = DPP_ADD(pd, 0x114, 0xf);  // row_shr:4
                pd = DPP_ADD(pd, 0x118, 0xf);  // row_shr:8

                if ((lane & 15) == 15) {
                    const int chain = b * 4 + (lane >> 4);
                    const float sil = sz[chain * 65 + tl];   // LDS, no VMEM
                    nt_store1(&out[(size_t)t * STRD_ + (size_t)g * CHB_ + chain],
                              pd * sil);
                }
            }
        }

        LDS_BARRIER();   // stage reads done; safe to overwrite next group
    }
}

// ---------------- Fallback (R4 single kernel) if ws too small -------------
__global__ __launch_bounds__(256, 2) void slot_elman_fallback(
    const float* __restrict__ x, const float* __restrict__ z,
    const float* __restrict__ h0, const float* __restrict__ dl,
    const float* __restrict__ Bm, const float* __restrict__ C,
    float* __restrict__ out, float* __restrict__ h)
{
    const int nb  = gridDim.x;
    const int cpx = nb >> 3;
    const int bid = blockIdx.x;
    const int swz = (bid & 7) * cpx + (bid >> 3);

    const int wave = swz * (blockDim.x >> 6) + (threadIdx.x >> 6);
    const int lane = threadIdx.x & 63;
    const int bd = wave & (NCH_ - 1);
    const int d  = bd & (D_ - 1);
    const int ds = d * S_ + lane;

    const float decay = sigmoidf_(dl[ds]);
    const float Bv    = Bm[ds];
    const float Cv    = C[lane];

    float hv = h0[(size_t)bd * S_ + lane];
    h[(size_t)bd * S_ + lane] = hv;

    const float* xg_p = x + (size_t)lane * STRD_ + bd;
    const float* zg_p = z + (size_t)lane * STRD_ + bd;
    float*       hp = h + (size_t)(NCH_ * S_) + (size_t)bd * S_ + lane;
    float*       op = out + (size_t)lane * STRD_ + bd;

    float xgA = xg_p[0];
    float zgA = zg_p[0];

    for (int blk = 0; blk < NSEG_; ++blk) {
        const int tb = blk * SEG_;
        const int tbn = (blk + 1 < NSEG_) ? (tb + SEG_) : tb;
        const float xgB = xg_p[(size_t)tbn * STRD_];
        const float zgB = zg_p[(size_t)tbn * STRD_];

        const float sgv = zgA * sigmoidf_(zgA);
        float outacc = 0.0f;

        #pragma unroll 8
        for (int i = 0; i < SEG_; ++i) {
            const float xs = readlane_f(xgA, i);
            hv = fmaf(decay, hv, Bv * xs);
            hp[(size_t)(tb + i) * (NCH_ * S_)] = hv;

            float p = hv * Cv;
            p = DPP_ADD(p, 0x111, 0xf);
            p = DPP_ADD(p, 0x112, 0xf);
            p = DPP_ADD(p, 0x114, 0xf);
            p = DPP_ADD(p, 0x118, 0xf);
            p = DPP_ADD(p, 0x142, 0xa);
            p = DPP_ADD(p, 0x143, 0xc);

            const float ov = p * readlane_f(sgv, i);
            const float bc = readlane_f(ov, 63);
            outacc = (lane == i) ? bc : outacc;
        }
        op[(size_t)tb * STRD_] = outacc;
        xgA = xgB; zgA = zgB;
    }
}

extern "C" void kernel_launch(void* const* d_in, const int* in_sizes, int n_in,
                              void* d_out, int out_size, void* d_ws, size_t ws_size,
                              hipStream_t stream) {
    const float* x  = (const float*)d_in[0];   // [T,Bb,D]
    const float* z  = (const float*)d_in[1];   // [T,Bb,D]
    const float* h0 = (const float*)d_in[2];   // [Bb,D,S]
    const float* dl = (const float*)d_in[3];   // [D,S]
    const float* Bm = (const float*)d_in[4];   // [D,S]
    const float* C  = (const float*)d_in[5];   // [S]

    float* out = (float*)d_out;                            // [T,Bb,D]
    float* h   = (float*)d_out + (size_t)T_ * BB_ * D_;    // [T+1,Bb,D,S]

    if (ws_size >= WS_NEED_) {
        float* ws = (float*)d_ws;
        const int waves1 = NCH_ * NSEG_;          // 32768
        const int grid1  = waves1 * 64 / 256;     // 8192
        hipLaunchKernelGGL(slot_elman_pass1, dim3(grid1), dim3(256), 0, stream,
                           x, dl, Bm, ws);
        const int grid2  = (NCH_ / CHB_) * NSEG_; // 128 * 16 = 2048
        hipLaunchKernelGGL(slot_elman_pass2, dim3(grid2), dim3(1024), 0, stream,
                           x, z, h0, dl, Bm, C, ws, out, h);
    } else {
        const int waves = NCH_;                   // 2048
        const int grid  = waves * 64 / 256;       // 512
        hipLaunchKernelGGL(slot_elman_fallback, dim3(grid), dim3(256), 0, stream,
                           x, z, h0, dl, Bm, C, out, h);
    }
}

// Round 15
// 137.200 us; speedup vs baseline: 1.0522x; 1.0221x over previous
//
#include <hip/hip_runtime.h>

// SlotElmanCell: T=1024, Bb=2, D=1024, S=64
//   decay = sigmoid(decay_logits)            [D,S]
//   h[t+1] = decay*h[t] + B*x[t]             [Bb,D,S]
//   out[t] = (h[t+1] . C) * silu(z[t])       [Bb,D]
// Outputs (concat flat): out [T,Bb,D] then h [T+1,Bb,D,S]  (f32)
//
// R15 = R12 (best, 114us; R13/R14 flush-restructures regressed and are
// reverted) with ONE change: block geometry 1024thr/16ch -> 512thr/8ch
// (CHB_=8, FG_=8, stage 16KB). The 2048-thread/CU cap allowed only 2
// resident blocks at 1024thr; at 512thr we get 4 blocks/CU, so compute
// and flush phases of different blocks interleave and the store stream
// stays fed. Step loop and write pattern byte-equivalent to R12.

#define T_    1024
#define BB_   2
#define D_    1024
#define S_    64
#define SEG_  64              // steps per segment
#define NSEG_ (T_ / SEG_)     // 16
#define NCH_  (BB_ * D_)      // 2048 chains
#define STRD_ (BB_ * D_)      // x/z stride between timesteps
#define CHB_  8               // chains per pass2 block
#define FG_   8               // steps per flush group
#define NGRP_ (NCH_ / CHB_)   // 256 chain groups
#define WS_NEED_ ((size_t)NCH_ * NSEG_ * S_ * 4)   // 8 MB

typedef float f32x4 __attribute__((ext_vector_type(4)));

// Barrier that does NOT drain vmcnt (LDS ordering only).
#define LDS_BARRIER() asm volatile("s_waitcnt lgkmcnt(0)\n\ts_barrier" ::: "memory")

// x + dpp_shifted(x); bound_ctrl=1 -> out-of-range sources read 0.
#define DPP_ADD(x, ctrl, rm) \
  ((x) + __int_as_float(__builtin_amdgcn_update_dpp( \
        0, __float_as_int(x), (ctrl), (rm), 0xf, true)))

__device__ __forceinline__ float readlane_f(float v, int lane) {
    return __int_as_float(__builtin_amdgcn_readlane(__float_as_int(v), lane));
}

__device__ __forceinline__ float sigmoidf_(float v) {
    return 1.0f / (1.0f + __expf(-v));
}

__device__ __forceinline__ void nt_store4(float* p, f32x4 v) {
    __builtin_nontemporal_store(v, (f32x4*)p);
}
__device__ __forceinline__ void nt_store1(float* p, float v) {
    __builtin_nontemporal_store(v, p);
}

// ---------------- Pass 1: per-segment local scans (zero init) -------------
__global__ __launch_bounds__(256, 8) void slot_elman_pass1(
    const float* __restrict__ x, const float* __restrict__ dl,
    const float* __restrict__ Bm, float* __restrict__ ws)
{
    const int wave = blockIdx.x * (blockDim.x >> 6) + (threadIdx.x >> 6);
    const int lane = threadIdx.x & 63;
    const int bd   = wave & (NCH_ - 1);     // chain
    const int seg  = wave >> 11;            // segment
    const int d    = bd & (D_ - 1);
    const int ds   = d * S_ + lane;

    const float decay = sigmoidf_(dl[ds]);
    const float Bv    = Bm[ds];

    const float xg = x[(size_t)(seg * SEG_ + lane) * STRD_ + bd];

    float hl = 0.0f;
    #pragma unroll
    for (int i = 0; i < SEG_; ++i)
        hl = fmaf(decay, hl, Bv * readlane_f(xg, i));

    ws[(size_t)(bd * NSEG_ + seg) * S_ + lane] = hl;   // regular store (re-read)
}

// ---------------- Pass 2: fold start state, scan, staged writes -----------
__global__ __launch_bounds__(512, 4) void slot_elman_pass2(
    const float* __restrict__ x, const float* __restrict__ z,
    const float* __restrict__ h0, const float* __restrict__ dl,
    const float* __restrict__ Bm, const float* __restrict__ C,
    const float* __restrict__ ws,
    float* __restrict__ out, float* __restrict__ h)
{
    __shared__ float stage[FG_ * CHB_ * S_];   // 16 KB -> 4 blocks/CU

    // Seg-major ordering (R7, confirmed): resident window (~1024 blocks)
    // = segs 0..3 with all 256 chain-groups -> contiguous 512KB sweeps.
    const int bid = blockIdx.x;
    const int seg = bid >> 8;                       // 0..15
    const int g   = bid & (NGRP_ - 1);              // chain group 0..255

    const int w    = threadIdx.x >> 6;              // wave 0..7
    const int lane = threadIdx.x & 63;              // slot s
    const int bd   = g * CHB_ + w;
    const int d    = bd & (D_ - 1);
    const int ds   = d * S_ + lane;

    const float decay = sigmoidf_(dl[ds]);
    const float Bv    = Bm[ds];
    const float Cv    = C[lane];

    // decay^64 by repeated squaring
    float dk = decay * decay;
    dk = dk * dk; dk = dk * dk; dk = dk * dk; dk = dk * dk;
    const float d64 = dk * dk;

    // Segment start state: h0 folded with previous segments' local sums.
    float hv = h0[(size_t)bd * S_ + lane];
    if (seg == 0)
        nt_store1(&h[(size_t)bd * S_ + lane], hv);  // h[0] slice

    const float* wp = ws + (size_t)bd * NSEG_ * S_ + lane;
    #pragma unroll
    for (int j = 0; j < NSEG_ - 1; ++j) {
        const float lj = wp[(size_t)j * S_];
        const float wgt = (j < seg) ? d64 : 1.0f;
        const float add = (j < seg) ? lj  : 0.0f;
        hv = fmaf(wgt, hv, add);
    }

    // Gathers: lane l covers t = seg*64 + l
    const float xgA = x[(size_t)(seg * SEG_ + lane) * STRD_ + bd];
    const float zgA = z[(size_t)(seg * SEG_ + lane) * STRD_ + bd];
    const float sgv = zgA * sigmoidf_(zgA);         // silu, lane = t

    float outacc = 0.0f;

    for (int f = 0; f < SEG_ / FG_; ++f) {          // 8 groups of 8 steps
        #pragma unroll
        for (int li = 0; li < FG_; ++li) {
            const int i = f * FG_ + li;             // segment-local step
            const float xs = readlane_f(xgA, i);

            hv = fmaf(decay, hv, Bv * xs);          // recurrence

            // Stage h row: [li][chain w][slot] -> 2-way bank alias (free)
            stage[(li * CHB_ + w) * S_ + lane] = hv;

            // Wave-wide sum of hv*Cv via DPP (pure VALU)
            float p = hv * Cv;
            p = DPP_ADD(p, 0x111, 0xf);  // row_shr:1
            p = DPP_ADD(p, 0x112, 0xf);  // row_shr:2
            p = DPP_ADD(p, 0x114, 0xf);  // row_shr:4
            p = DPP_ADD(p, 0x118, 0xf);  // row_shr:8
            p = DPP_ADD(p, 0x142, 0xa);  // row_bcast:15
            p = DPP_ADD(p, 0x143, 0xc);  // row_bcast:31 -> lane63 = total

            const float ov = p * readlane_f(sgv, i);
            const float bc = readlane_f(ov, 63);
            outacc = (lane == i) ? bc : outacc;     // deposit lane i
        }

        LDS_BARRIER();   // stage writes visible; global stores NOT drained

        // Flush: wave w takes t-slice li=w -> ONE contiguous 2KB chunk;
        // 256 same-seg blocks together cover the full 512KB t-slice.
        // Non-temporal: h is write-once, keep it out of L2.
        {
            const int t1 = seg * SEG_ + f * FG_ + w + 1;  // h slice index
            const float* src = &stage[w * CHB_ * S_];     // 512 floats
            float* dst = &h[((size_t)t1 * NCH_ + (size_t)g * CHB_) * S_];
            const int o = lane * 4;                 // 64 lanes x 4 floats
            nt_store4(dst + o,       *(const f32x4*)(src + o));
            nt_store4(dst + o + 256, *(const f32x4*)(src + o + 256));
        }

        LDS_BARRIER();   // stage reads done; safe to overwrite next group
    }

    // out staging: [t-local][chain] with pad-9 stride (conflict-free)
    stage[lane * 9 + w] = outacc;
    LDS_BARRIER();
    {
        const int tl = threadIdx.x >> 3;            // 0..63
        const int c  = threadIdx.x & 7;             // chain in group
        nt_store1(&out[(size_t)(seg * SEG_ + tl) * STRD_ + (size_t)g * CHB_ + c],
                  stage[tl * 9 + c]);
    }
}

// ---------------- Fallback (R4 single kernel) if ws too small -------------
__global__ __launch_bounds__(256, 2) void slot_elman_fallback(
    const float* __restrict__ x, const float* __restrict__ z,
    const float* __restrict__ h0, const float* __restrict__ dl,
    const float* __restrict__ Bm, const float* __restrict__ C,
    float* __restrict__ out, float* __restrict__ h)
{
    const int nb  = gridDim.x;
    const int cpx = nb >> 3;
    const int bid = blockIdx.x;
    const int swz = (bid & 7) * cpx + (bid >> 3);

    const int wave = swz * (blockDim.x >> 6) + (threadIdx.x >> 6);
    const int lane = threadIdx.x & 63;
    const int bd = wave & (NCH_ - 1);
    const int d  = bd & (D_ - 1);
    const int ds = d * S_ + lane;

    const float decay = sigmoidf_(dl[ds]);
    const float Bv    = Bm[ds];
    const float Cv    = C[lane];

    float hv = h0[(size_t)bd * S_ + lane];
    h[(size_t)bd * S_ + lane] = hv;

    const float* xg_p = x + (size_t)lane * STRD_ + bd;
    const float* zg_p = z + (size_t)lane * STRD_ + bd;
    float*       hp = h + (size_t)(NCH_ * S_) + (size_t)bd * S_ + lane;
    float*       op = out + (size_t)lane * STRD_ + bd;

    float xgA = xg_p[0];
    float zgA = zg_p[0];

    for (int blk = 0; blk < NSEG_; ++blk) {
        const int tb = blk * SEG_;
        const int tbn = (blk + 1 < NSEG_) ? (tb + SEG_) : tb;
        const float xgB = xg_p[(size_t)tbn * STRD_];
        const float zgB = zg_p[(size_t)tbn * STRD_];

        const float sgv = zgA * sigmoidf_(zgA);
        float outacc = 0.0f;

        #pragma unroll 8
        for (int i = 0; i < SEG_; ++i) {
            const float xs = readlane_f(xgA, i);
            hv = fmaf(decay, hv, Bv * xs);
            hp[(size_t)(tb + i) * (NCH_ * S_)] = hv;

            float p = hv * Cv;
            p = DPP_ADD(p, 0x111, 0xf);
            p = DPP_ADD(p, 0x112, 0xf);
            p = DPP_ADD(p, 0x114, 0xf);
            p = DPP_ADD(p, 0x118, 0xf);
            p = DPP_ADD(p, 0x142, 0xa);
            p = DPP_ADD(p, 0x143, 0xc);

            const float ov = p * readlane_f(sgv, i);
            const float bc = readlane_f(ov, 63);
            outacc = (lane == i) ? bc : outacc;
        }
        op[(size_t)tb * STRD_] = outacc;
        xgA = xgB; zgA = zgB;
    }
}

extern "C" void kernel_launch(void* const* d_in, const int* in_sizes, int n_in,
                              void* d_out, int out_size, void* d_ws, size_t ws_size,
                              hipStream_t stream) {
    const float* x  = (const float*)d_in[0];   // [T,Bb,D]
    const float* z  = (const float*)d_in[1];   // [T,Bb,D]
    const float* h0 = (const float*)d_in[2];   // [Bb,D,S]
    const float* dl = (const float*)d_in[3];   // [D,S]
    const float* Bm = (const float*)d_in[4];   // [D,S]
    const float* C  = (const float*)d_in[5];   // [S]

    float* out = (float*)d_out;                            // [T,Bb,D]
    float* h   = (float*)d_out + (size_t)T_ * BB_ * D_;    // [T+1,Bb,D,S]

    if (ws_size >= WS_NEED_) {
        float* ws = (float*)d_ws;
        const int waves1 = NCH_ * NSEG_;          // 32768
        const int grid1  = waves1 * 64 / 256;     // 8192
        hipLaunchKernelGGL(slot_elman_pass1, dim3(grid1), dim3(256), 0, stream,
                           x, dl, Bm, ws);
        const int grid2  = NGRP_ * NSEG_;         // 256 * 16 = 4096
        hipLaunchKernelGGL(slot_elman_pass2, dim3(grid2), dim3(512), 0, stream,
                           x, z, h0, dl, Bm, C, ws, out, h);
    } else {
        const int waves = NCH_;                   // 2048
        const int grid  = waves * 64 / 256;       // 512
        hipLaunchKernelGGL(slot_elman_fallback, dim3(grid), dim3(256), 0, stream,
                           x, z, h0, dl, Bm, C, out, h);
    }
}

// Round 16
// 130.948 us; speedup vs baseline: 1.1025x; 1.0477x over previous
//
#include <hip/hip_runtime.h>

// SlotElmanCell: T=1024, Bb=2, D=1024, S=64
//   decay = sigmoid(decay_logits)            [D,S]
//   h[t+1] = decay*h[t] + B*x[t]             [Bb,D,S]
//   out[t] = (h[t+1] . C) * silu(z[t])       [Bb,D]
// Outputs (concat flat): out [T,Bb,D] then h [T+1,Bb,D,S]  (f32)
//
// R16 = R12 geometry (1024thr/CHB16/FG16, best=114us; R13/R14/R15 phase
// restructures all regressed) with ONE change: grid 2048 -> 512 blocks,
// each block runs 4 segments {sr, sr+4, sr+8, sr+12} (one per generation).
//  - h0 + all 15 ws slices loaded ONCE into registers (fold = 15 reg-FMAs
//    per segment; ws re-read traffic /4)
//  - next segment's x/z gathers issued at current segment top, consumed
//    4 flush-groups later -> generation-start read stall hidden
//  - all 512 blocks co-resident (2/CU); equal per-generation work keeps
//    the 4-seg write window without grid.sync (R9's failure mode).

#define T_    1024
#define BB_   2
#define D_    1024
#define S_    64
#define SEG_  64              // steps per segment
#define NSEG_ (T_ / SEG_)     // 16
#define NCH_  (BB_ * D_)      // 2048 chains
#define STRD_ (BB_ * D_)      // x/z stride between timesteps
#define CHB_  16              // chains per pass2 block
#define FG_   16              // steps per flush group
#define WS_NEED_ ((size_t)NCH_ * NSEG_ * S_ * 4)   // 8 MB

typedef float f32x4 __attribute__((ext_vector_type(4)));

// Barrier that does NOT drain vmcnt (LDS ordering only).
#define LDS_BARRIER() asm volatile("s_waitcnt lgkmcnt(0)\n\ts_barrier" ::: "memory")

// x + dpp_shifted(x); bound_ctrl=1 -> out-of-range sources read 0.
#define DPP_ADD(x, ctrl, rm) \
  ((x) + __int_as_float(__builtin_amdgcn_update_dpp( \
        0, __float_as_int(x), (ctrl), (rm), 0xf, true)))

__device__ __forceinline__ float readlane_f(float v, int lane) {
    return __int_as_float(__builtin_amdgcn_readlane(__float_as_int(v), lane));
}

__device__ __forceinline__ float sigmoidf_(float v) {
    return 1.0f / (1.0f + __expf(-v));
}

__device__ __forceinline__ void nt_store4(float* p, f32x4 v) {
    __builtin_nontemporal_store(v, (f32x4*)p);
}
__device__ __forceinline__ void nt_store1(float* p, float v) {
    __builtin_nontemporal_store(v, p);
}

// ---------------- Pass 1: per-segment local scans (zero init) -------------
__global__ __launch_bounds__(256, 8) void slot_elman_pass1(
    const float* __restrict__ x, const float* __restrict__ dl,
    const float* __restrict__ Bm, float* __restrict__ ws)
{
    const int wave = blockIdx.x * (blockDim.x >> 6) + (threadIdx.x >> 6);
    const int lane = threadIdx.x & 63;
    const int bd   = wave & (NCH_ - 1);     // chain
    const int seg  = wave >> 11;            // segment
    const int d    = bd & (D_ - 1);
    const int ds   = d * S_ + lane;

    const float decay = sigmoidf_(dl[ds]);
    const float Bv    = Bm[ds];

    const float xg = x[(size_t)(seg * SEG_ + lane) * STRD_ + bd];

    float hl = 0.0f;
    #pragma unroll
    for (int i = 0; i < SEG_; ++i)
        hl = fmaf(decay, hl, Bv * readlane_f(xg, i));

    ws[(size_t)(bd * NSEG_ + seg) * S_ + lane] = hl;   // regular store (re-read)
}

// ---------------- Pass 2: 4 segments per block, staged writes -------------
__global__ __launch_bounds__(1024, 8) void slot_elman_pass2(
    const float* __restrict__ x, const float* __restrict__ z,
    const float* __restrict__ h0, const float* __restrict__ dl,
    const float* __restrict__ Bm, const float* __restrict__ C,
    const float* __restrict__ ws,
    float* __restrict__ out, float* __restrict__ h)
{
    __shared__ float stage[FG_ * CHB_ * S_];   // 64 KB -> 2 blocks/CU

    const int bid = blockIdx.x;                     // 0..511 (all resident)
    const int g   = bid & 127;                      // chain group
    const int sr  = bid >> 7;                       // seg sub-row 0..3

    const int w    = threadIdx.x >> 6;              // wave 0..15
    const int lane = threadIdx.x & 63;              // slot s
    const int bd   = g * CHB_ + w;
    const int d    = bd & (D_ - 1);
    const int ds   = d * S_ + lane;

    const float decay = sigmoidf_(dl[ds]);
    const float Bv    = Bm[ds];
    const float Cv    = C[lane];

    // decay^64 by repeated squaring
    float dk = decay * decay;
    dk = dk * dk; dk = dk * dk; dk = dk * dk; dk = dk * dk;
    const float d64 = dk * dk;

    // Prologue: h0 + ALL 15 ws slices into registers (one read, 4 reuses)
    const float hq = h0[(size_t)bd * S_ + lane];
    if (sr == 0)
        nt_store1(&h[(size_t)bd * S_ + lane], hq);  // h[0] slice, once

    float wsreg[NSEG_ - 1];
    {
        const float* wp = ws + (size_t)bd * NSEG_ * S_ + lane;
        #pragma unroll
        for (int j = 0; j < NSEG_ - 1; ++j)
            wsreg[j] = wp[(size_t)j * S_];
    }

    // First segment's gathers: lane l covers t = seg*64 + l
    float xg = x[(size_t)(sr * SEG_ + lane) * STRD_ + bd];
    float zg = z[(size_t)(sr * SEG_ + lane) * STRD_ + bd];

    #pragma unroll
    for (int js = 0; js < 4; ++js) {                // generation loop
        const int seg = 4 * js + sr;

        // Start state: fold h0 + prior local sums (pure register FMAs)
        float hv = hq;
        #pragma unroll
        for (int j = 0; j < NSEG_ - 1; ++j) {
            const float wgt = (j < seg) ? d64 : 1.0f;
            const float add = (j < seg) ? wsreg[j] : 0.0f;
            hv = fmaf(wgt, hv, add);
        }

        const float xgc = xg;                       // current segment x
        const float sgv = zg * sigmoidf_(zg);       // silu, lane = t

        // Prefetch NEXT segment's gathers (consumed 4 flush-groups later)
        if (js < 3) {
            const int ns = seg + 4;
            xg = x[(size_t)(ns * SEG_ + lane) * STRD_ + bd];
            zg = z[(size_t)(ns * SEG_ + lane) * STRD_ + bd];
        }

        float outacc = 0.0f;

        for (int f = 0; f < SEG_ / FG_; ++f) {      // 4 groups of 16 steps
            #pragma unroll
            for (int li = 0; li < FG_; ++li) {
                const int i = f * FG_ + li;         // segment-local step
                const float xs = readlane_f(xgc, i);

                hv = fmaf(decay, hv, Bv * xs);      // recurrence

                // Stage h row: [li][chain w][slot]
                stage[(li * CHB_ + w) * S_ + lane] = hv;

                // Wave-wide sum of hv*Cv via DPP (pure VALU)
                float p = hv * Cv;
                p = DPP_ADD(p, 0x111, 0xf);  // row_shr:1
                p = DPP_ADD(p, 0x112, 0xf);  // row_shr:2
                p = DPP_ADD(p, 0x114, 0xf);  // row_shr:4
                p = DPP_ADD(p, 0x118, 0xf);  // row_shr:8
                p = DPP_ADD(p, 0x142, 0xa);  // row_bcast:15
                p = DPP_ADD(p, 0x143, 0xc);  // row_bcast:31 -> lane63

                const float ov = p * readlane_f(sgv, i);
                const float bc = readlane_f(ov, 63);
                outacc = (lane == i) ? bc : outacc; // deposit lane i
            }

            LDS_BARRIER();   // stage visible; global stores NOT drained

            // Flush: wave w -> t-slice li=w, ONE contiguous 4KB chunk (nt)
            {
                const int t1 = seg * SEG_ + f * FG_ + w + 1;
                const float* src = &stage[w * CHB_ * S_];
                float* dst = &h[((size_t)t1 * NCH_ + (size_t)g * CHB_) * S_];
                const int o = lane * 4;             // 64 lanes x 4 floats
                nt_store4(dst + o,       *(const f32x4*)(src + o));
                nt_store4(dst + o + 256, *(const f32x4*)(src + o + 256));
                nt_store4(dst + o + 512, *(const f32x4*)(src + o + 512));
                nt_store4(dst + o + 768, *(const f32x4*)(src + o + 768));
            }

            LDS_BARRIER();   // stage reads done; safe to overwrite
        }

        // out staging: [t-local][chain] with pad-17 stride (conflict-free)
        stage[lane * 17 + w] = outacc;
        LDS_BARRIER();
        {
            const int tl = threadIdx.x >> 4;        // 0..63
            const int c  = threadIdx.x & 15;        // chain in group
            nt_store1(&out[(size_t)(seg * SEG_ + tl) * STRD_ + (size_t)g * CHB_ + c],
                      stage[tl * 17 + c]);
        }
        LDS_BARRIER();       // protect stage before next segment's writes
    }
}

// ---------------- Fallback (R4 single kernel) if ws too small -------------
__global__ __launch_bounds__(256, 2) void slot_elman_fallback(
    const float* __restrict__ x, const float* __restrict__ z,
    const float* __restrict__ h0, const float* __restrict__ dl,
    const float* __restrict__ Bm, const float* __restrict__ C,
    float* __restrict__ out, float* __restrict__ h)
{
    const int nb  = gridDim.x;
    const int cpx = nb >> 3;
    const int bid = blockIdx.x;
    const int swz = (bid & 7) * cpx + (bid >> 3);

    const int wave = swz * (blockDim.x >> 6) + (threadIdx.x >> 6);
    const int lane = threadIdx.x & 63;
    const int bd = wave & (NCH_ - 1);
    const int d  = bd & (D_ - 1);
    const int ds = d * S_ + lane;

    const float decay = sigmoidf_(dl[ds]);
    const float Bv    = Bm[ds];
    const float Cv    = C[lane];

    float hv = h0[(size_t)bd * S_ + lane];
    h[(size_t)bd * S_ + lane] = hv;

    const float* xg_p = x + (size_t)lane * STRD_ + bd;
    const float* zg_p = z + (size_t)lane * STRD_ + bd;
    float*       hp = h + (size_t)(NCH_ * S_) + (size_t)bd * S_ + lane;
    float*       op = out + (size_t)lane * STRD_ + bd;

    float xgA = xg_p[0];
    float zgA = zg_p[0];

    for (int blk = 0; blk < NSEG_; ++blk) {
        const int tb = blk * SEG_;
        const int tbn = (blk + 1 < NSEG_) ? (tb + SEG_) : tb;
        const float xgB = xg_p[(size_t)tbn * STRD_];
        const float zgB = zg_p[(size_t)tbn * STRD_];

        const float sgv = zgA * sigmoidf_(zgA);
        float outacc = 0.0f;

        #pragma unroll 8
        for (int i = 0; i < SEG_; ++i) {
            const float xs = readlane_f(xgA, i);
            hv = fmaf(decay, hv, Bv * xs);
            hp[(size_t)(tb + i) * (NCH_ * S_)] = hv;

            float p = hv * Cv;
            p = DPP_ADD(p, 0x111, 0xf);
            p = DPP_ADD(p, 0x112, 0xf);
            p = DPP_ADD(p, 0x114, 0xf);
            p = DPP_ADD(p, 0x118, 0xf);
            p = DPP_ADD(p, 0x142, 0xa);
            p = DPP_ADD(p, 0x143, 0xc);

            const float ov = p * readlane_f(sgv, i);
            const float bc = readlane_f(ov, 63);
            outacc = (lane == i) ? bc : outacc;
        }
        op[(size_t)tb * STRD_] = outacc;
        xgA = xgB; zgA = zgB;
    }
}

extern "C" void kernel_launch(void* const* d_in, const int* in_sizes, int n_in,
                              void* d_out, int out_size, void* d_ws, size_t ws_size,
                              hipStream_t stream) {
    const float* x  = (const float*)d_in[0];   // [T,Bb,D]
    const float* z  = (const float*)d_in[1];   // [T,Bb,D]
    const float* h0 = (const float*)d_in[2];   // [Bb,D,S]
    const float* dl = (const float*)d_in[3];   // [D,S]
    const float* Bm = (const float*)d_in[4];   // [D,S]
    const float* C  = (const float*)d_in[5];   // [S]

    float* out = (float*)d_out;                            // [T,Bb,D]
    float* h   = (float*)d_out + (size_t)T_ * BB_ * D_;    // [T+1,Bb,D,S]

    if (ws_size >= WS_NEED_) {
        float* ws = (float*)d_ws;
        const int waves1 = NCH_ * NSEG_;          // 32768
        const int grid1  = waves1 * 64 / 256;     // 8192
        hipLaunchKernelGGL(slot_elman_pass1, dim3(grid1), dim3(256), 0, stream,
                           x, dl, Bm, ws);
        const int grid2  = 512;                   // 128 groups x 4 sub-rows
        hipLaunchKernelGGL(slot_elman_pass2, dim3(grid2), dim3(1024), 0, stream,
                           x, z, h0, dl, Bm, C, ws, out, h);
    } else {
        const int waves = NCH_;                   // 2048
        const int grid  = waves * 64 / 256;       // 512
        hipLaunchKernelGGL(slot_elman_fallback, dim3(grid), dim3(256), 0, stream,
                           x, z, h0, dl, Bm, C, out, h);
    }
}

// Round 17
// 114.129 us; speedup vs baseline: 1.2649x; 1.1474x over previous
//
#include <hip/hip_runtime.h>

// SlotElmanCell: T=1024, Bb=2, D=1024, S=64
//   decay = sigmoid(decay_logits)            [D,S]
//   h[t+1] = decay*h[t] + B*x[t]             [Bb,D,S]
//   out[t] = (h[t+1] . C) * silu(z[t])       [Bb,D]
// Outputs (concat flat): out [T,Bb,D] then h [T+1,Bb,D,S]  (f32)
//
// R17 = exact revert to R12 (best measured: 114.0us). R13/R14/R15/R16
// restructures all regressed; R12's structure is the empirical optimum:
//  - two passes: pass1 local scans -> ws; pass2 fold + rescan + write
//  - pass2: 2048 blocks seg-major (dispatch order enforces the narrow
//    4-segment device write window, R7's confirmed lever)
//  - 16-step LDS-staged groups, per-wave 4KB contiguous nt h-flushes
//    (R12's confirmed lever: nt keeps write-once streams out of L2)
//  - lgkmcnt-only barriers (stores never drained inside the loop)

#define T_    1024
#define BB_   2
#define D_    1024
#define S_    64
#define SEG_  64              // steps per segment
#define NSEG_ (T_ / SEG_)     // 16
#define NCH_  (BB_ * D_)      // 2048 chains
#define STRD_ (BB_ * D_)      // x/z stride between timesteps
#define CHB_  16              // chains per pass2 block
#define FG_   16              // steps per flush group
#define WS_NEED_ ((size_t)NCH_ * NSEG_ * S_ * 4)   // 8 MB

typedef float f32x4 __attribute__((ext_vector_type(4)));

// Barrier that does NOT drain vmcnt (LDS ordering only).
#define LDS_BARRIER() asm volatile("s_waitcnt lgkmcnt(0)\n\ts_barrier" ::: "memory")

// x + dpp_shifted(x); bound_ctrl=1 -> out-of-range sources read 0.
#define DPP_ADD(x, ctrl, rm) \
  ((x) + __int_as_float(__builtin_amdgcn_update_dpp( \
        0, __float_as_int(x), (ctrl), (rm), 0xf, true)))

__device__ __forceinline__ float readlane_f(float v, int lane) {
    return __int_as_float(__builtin_amdgcn_readlane(__float_as_int(v), lane));
}

__device__ __forceinline__ float sigmoidf_(float v) {
    return 1.0f / (1.0f + __expf(-v));
}

__device__ __forceinline__ void nt_store4(float* p, f32x4 v) {
    __builtin_nontemporal_store(v, (f32x4*)p);
}
__device__ __forceinline__ void nt_store1(float* p, float v) {
    __builtin_nontemporal_store(v, p);
}

// ---------------- Pass 1: per-segment local scans (zero init) -------------
__global__ __launch_bounds__(256, 8) void slot_elman_pass1(
    const float* __restrict__ x, const float* __restrict__ dl,
    const float* __restrict__ Bm, float* __restrict__ ws)
{
    const int wave = blockIdx.x * (blockDim.x >> 6) + (threadIdx.x >> 6);
    const int lane = threadIdx.x & 63;
    const int bd   = wave & (NCH_ - 1);     // chain
    const int seg  = wave >> 11;            // segment
    const int d    = bd & (D_ - 1);
    const int ds   = d * S_ + lane;

    const float decay = sigmoidf_(dl[ds]);
    const float Bv    = Bm[ds];

    const float xg = x[(size_t)(seg * SEG_ + lane) * STRD_ + bd];

    float hl = 0.0f;
    #pragma unroll
    for (int i = 0; i < SEG_; ++i)
        hl = fmaf(decay, hl, Bv * readlane_f(xg, i));

    ws[(size_t)(bd * NSEG_ + seg) * S_ + lane] = hl;   // regular store (re-read)
}

// ---------------- Pass 2: fold start state, scan, staged writes -----------
__global__ __launch_bounds__(1024, 8) void slot_elman_pass2(
    const float* __restrict__ x, const float* __restrict__ z,
    const float* __restrict__ h0, const float* __restrict__ dl,
    const float* __restrict__ Bm, const float* __restrict__ C,
    const float* __restrict__ ws,
    float* __restrict__ out, float* __restrict__ h)
{
    __shared__ float stage[FG_ * CHB_ * S_];   // 64 KB

    // Seg-major ordering (R7, confirmed): resident window = few segments
    // with all 128 chain-groups -> contiguous 512KB t-slice sweeps.
    const int bid = blockIdx.x;
    const int seg = bid >> 7;                       // 0..15
    const int g   = bid & 127;                      // chain group

    const int w    = threadIdx.x >> 6;              // wave 0..15
    const int lane = threadIdx.x & 63;              // slot s
    const int bd   = g * CHB_ + w;
    const int d    = bd & (D_ - 1);
    const int ds   = d * S_ + lane;

    const float decay = sigmoidf_(dl[ds]);
    const float Bv    = Bm[ds];
    const float Cv    = C[lane];

    // decay^64 by repeated squaring
    float dk = decay * decay;
    dk = dk * dk; dk = dk * dk; dk = dk * dk; dk = dk * dk;
    const float d64 = dk * dk;

    // Segment start state: h0 folded with previous segments' local sums.
    float hv = h0[(size_t)bd * S_ + lane];
    if (seg == 0)
        nt_store1(&h[(size_t)bd * S_ + lane], hv);  // h[0] slice

    const float* wp = ws + (size_t)bd * NSEG_ * S_ + lane;
    #pragma unroll
    for (int j = 0; j < NSEG_ - 1; ++j) {
        const float lj = wp[(size_t)j * S_];
        const float wgt = (j < seg) ? d64 : 1.0f;
        const float add = (j < seg) ? lj  : 0.0f;
        hv = fmaf(wgt, hv, add);
    }

    // Gathers: lane l covers t = seg*64 + l
    const float xgA = x[(size_t)(seg * SEG_ + lane) * STRD_ + bd];
    const float zgA = z[(size_t)(seg * SEG_ + lane) * STRD_ + bd];
    const float sgv = zgA * sigmoidf_(zgA);         // silu, lane = t

    float outacc = 0.0f;

    for (int f = 0; f < SEG_ / FG_; ++f) {          // 4 groups of 16 steps
        #pragma unroll
        for (int li = 0; li < FG_; ++li) {
            const int i = f * FG_ + li;             // segment-local step
            const float xs = readlane_f(xgA, i);

            hv = fmaf(decay, hv, Bv * xs);          // recurrence

            // Stage h row: [li][chain w][slot] -> 2-way bank alias (free)
            stage[(li * CHB_ + w) * S_ + lane] = hv;

            // Wave-wide sum of hv*Cv via DPP (pure VALU)
            float p = hv * Cv;
            p = DPP_ADD(p, 0x111, 0xf);  // row_shr:1
            p = DPP_ADD(p, 0x112, 0xf);  // row_shr:2
            p = DPP_ADD(p, 0x114, 0xf);  // row_shr:4
            p = DPP_ADD(p, 0x118, 0xf);  // row_shr:8
            p = DPP_ADD(p, 0x142, 0xa);  // row_bcast:15
            p = DPP_ADD(p, 0x143, 0xc);  // row_bcast:31 -> lane63 = total

            const float ov = p * readlane_f(sgv, i);
            const float bc = readlane_f(ov, 63);
            outacc = (lane == i) ? bc : outacc;     // deposit lane i
        }

        LDS_BARRIER();   // stage writes visible; global stores NOT drained

        // Flush: wave w takes t-slice li=w -> ONE contiguous 4KB chunk;
        // 128 same-seg blocks together cover the full 512KB t-slice.
        // Non-temporal: h is write-once, keep it out of L2.
        {
            const int t1 = seg * SEG_ + f * FG_ + w + 1;  // h slice index
            const float* src = &stage[w * CHB_ * S_];
            float* dst = &h[((size_t)t1 * NCH_ + (size_t)g * CHB_) * S_];
            const int o = lane * 4;                 // 64 lanes x 4 floats
            nt_store4(dst + o,       *(const f32x4*)(src + o));
            nt_store4(dst + o + 256, *(const f32x4*)(src + o + 256));
            nt_store4(dst + o + 512, *(const f32x4*)(src + o + 512));
            nt_store4(dst + o + 768, *(const f32x4*)(src + o + 768));
        }

        LDS_BARRIER();   // stage reads done; safe to overwrite next group
    }

    // out staging: [t-local][chain] with pad-17 stride (conflict-free)
    stage[lane * 17 + w] = outacc;
    LDS_BARRIER();
    {
        const int tl = threadIdx.x >> 4;            // 0..63
        const int c  = threadIdx.x & 15;            // chain in group
        nt_store1(&out[(size_t)(seg * SEG_ + tl) * STRD_ + (size_t)g * CHB_ + c],
                  stage[tl * 17 + c]);
    }
}

// ---------------- Fallback (R4 single kernel) if ws too small -------------
__global__ __launch_bounds__(256, 2) void slot_elman_fallback(
    const float* __restrict__ x, const float* __restrict__ z,
    const float* __restrict__ h0, const float* __restrict__ dl,
    const float* __restrict__ Bm, const float* __restrict__ C,
    float* __restrict__ out, float* __restrict__ h)
{
    const int nb  = gridDim.x;
    const int cpx = nb >> 3;
    const int bid = blockIdx.x;
    const int swz = (bid & 7) * cpx + (bid >> 3);

    const int wave = swz * (blockDim.x >> 6) + (threadIdx.x >> 6);
    const int lane = threadIdx.x & 63;
    const int bd = wave & (NCH_ - 1);
    const int d  = bd & (D_ - 1);
    const int ds = d * S_ + lane;

    const float decay = sigmoidf_(dl[ds]);
    const float Bv    = Bm[ds];
    const float Cv    = C[lane];

    float hv = h0[(size_t)bd * S_ + lane];
    h[(size_t)bd * S_ + lane] = hv;

    const float* xg_p = x + (size_t)lane * STRD_ + bd;
    const float* zg_p = z + (size_t)lane * STRD_ + bd;
    float*       hp = h + (size_t)(NCH_ * S_) + (size_t)bd * S_ + lane;
    float*       op = out + (size_t)lane * STRD_ + bd;

    float xgA = xg_p[0];
    float zgA = zg_p[0];

    for (int blk = 0; blk < NSEG_; ++blk) {
        const int tb = blk * SEG_;
        const int tbn = (blk + 1 < NSEG_) ? (tb + SEG_) : tb;
        const float xgB = xg_p[(size_t)tbn * STRD_];
        const float zgB = zg_p[(size_t)tbn * STRD_];

        const float sgv = zgA * sigmoidf_(zgA);
        float outacc = 0.0f;

        #pragma unroll 8
        for (int i = 0; i < SEG_; ++i) {
            const float xs = readlane_f(xgA, i);
            hv = fmaf(decay, hv, Bv * xs);
            hp[(size_t)(tb + i) * (NCH_ * S_)] = hv;

            float p = hv * Cv;
            p = DPP_ADD(p, 0x111, 0xf);
            p = DPP_ADD(p, 0x112, 0xf);
            p = DPP_ADD(p, 0x114, 0xf);
            p = DPP_ADD(p, 0x118, 0xf);
            p = DPP_ADD(p, 0x142, 0xa);
            p = DPP_ADD(p, 0x143, 0xc);

            const float ov = p * readlane_f(sgv, i);
            const float bc = readlane_f(ov, 63);
            outacc = (lane == i) ? bc : outacc;
        }
        op[(size_t)tb * STRD_] = outacc;
        xgA = xgB; zgA = zgB;
    }
}

extern "C" void kernel_launch(void* const* d_in, const int* in_sizes, int n_in,
                              void* d_out, int out_size, void* d_ws, size_t ws_size,
                              hipStream_t stream) {
    const float* x  = (const float*)d_in[0];   // [T,Bb,D]
    const float* z  = (const float*)d_in[1];   // [T,Bb,D]
    const float* h0 = (const float*)d_in[2];   // [Bb,D,S]
    const float* dl = (const float*)d_in[3];   // [D,S]
    const float* Bm = (const float*)d_in[4];   // [D,S]
    const float* C  = (const float*)d_in[5];   // [S]

    float* out = (float*)d_out;                            // [T,Bb,D]
    float* h   = (float*)d_out + (size_t)T_ * BB_ * D_;    // [T+1,Bb,D,S]

    if (ws_size >= WS_NEED_) {
        float* ws = (float*)d_ws;
        const int waves1 = NCH_ * NSEG_;          // 32768
        const int grid1  = waves1 * 64 / 256;     // 8192
        hipLaunchKernelGGL(slot_elman_pass1, dim3(grid1), dim3(256), 0, stream,
                           x, dl, Bm, ws);
        const int grid2  = (NCH_ / CHB_) * NSEG_; // 128 * 16 = 2048
        hipLaunchKernelGGL(slot_elman_pass2, dim3(grid2), dim3(1024), 0, stream,
                           x, z, h0, dl, Bm, C, ws, out, h);
    } else {
        const int waves = NCH_;                   // 2048
        const int grid  = waves * 64 / 256;       // 512
        hipLaunchKernelGGL(slot_elman_fallback, dim3(grid), dim3(256), 0, stream,
                           x, z, h0, dl, Bm, C, out, h);
    }
}